// Round 7
// baseline (185.133 us; speedup 1.0000x reference)
//
#include <hip/hip_runtime.h>
#include <hip/hip_bf16.h>

#define NDIM   512
#define NPOS   1024   // 32*32
#define NB     8
#define INNER  1536
#define DHEAD  64

typedef __attribute__((ext_vector_type(8))) short bf8v;   // 8 bf16 = 4 VGPRs
typedef __attribute__((ext_vector_type(4))) float f4v;

__device__ __forceinline__ f4v mfma16(bf8v a, bf8v b, f4v c) {
    return __builtin_amdgcn_mfma_f32_16x16x32_bf16(a, b, c, 0, 0, 0);
}

__device__ __forceinline__ unsigned short f2bs(float v) {
    __hip_bfloat16 h = __float2bfloat16(v);   // RNE
    return *reinterpret_cast<unsigned short*>(&h);
}

// async global->LDS, 16B per lane; lds dst = wave-uniform base + lane*16
__device__ __forceinline__ void gl_lds16(const unsigned short* g, unsigned short* l) {
    __builtin_amdgcn_global_load_lds(
        (const __attribute__((address_space(1))) void*)g,
        (__attribute__((address_space(3))) void*)l,
        16, 0, 0);
}

// ---------------- K1: fused LN stats + normalize + cast + transpose -------
// xnT[b][n][c] = (x[b][c][n] - mean[b,n]) * rstd[b,n] * gamma[c]   (bf16)
__global__ __launch_bounds__(256) void ln_xnorm_kernel(
    const float* __restrict__ x, const float* __restrict__ gamma,
    unsigned short* __restrict__ xnT)
{
    __shared__ float ssum[4][64];
    __shared__ float ssq[4][64];
    __shared__ float mean_s[64];
    __shared__ float rstd_s[64];
    __shared__ unsigned short tile[64][72];

    const int b = blockIdx.y;
    const int n0 = blockIdx.x * 64;
    const int t = threadIdx.x;

    {
        const int ln = t & 63, cg = t >> 6;
        const float* xp = x + (size_t)b * NDIM * NPOS + n0 + ln;
        float s = 0.f, ss = 0.f;
        for (int c = cg * 128; c < cg * 128 + 128; ++c) {
            float v = xp[(size_t)c * NPOS];
            s += v; ss += v * v;
        }
        ssum[cg][ln] = s; ssq[cg][ln] = ss;
    }
    __syncthreads();
    if (t < 64) {
        float st = ssum[0][t] + ssum[1][t] + ssum[2][t] + ssum[3][t];
        float sq = ssq[0][t] + ssq[1][t] + ssq[2][t] + ssq[3][t];
        float m = st * (1.0f / NDIM);
        float var = sq * (1.0f / NDIM) - m * m;
        mean_s[t] = m;
        rstd_s[t] = rsqrtf(var + 1e-5f);
    }
    __syncthreads();

    const int cl = t >> 2, nq = (t & 3) * 16;
    const int n = t >> 2, cq = (t & 3) * 16;
    for (int c0 = 0; c0 < NDIM; c0 += 64) {
        const float g = gamma[c0 + cl];
        const float* xp = x + ((size_t)b * NDIM + c0 + cl) * NPOS + n0 + nq;
#pragma unroll
        for (int q = 0; q < 4; ++q) {
            float4 v = *(const float4*)(xp + q * 4);
            float4 m = *(const float4*)&mean_s[nq + q * 4];
            float4 r = *(const float4*)&rstd_s[nq + q * 4];
            tile[nq + q * 4 + 0][cl] = f2bs((v.x - m.x) * r.x * g);
            tile[nq + q * 4 + 1][cl] = f2bs((v.y - m.y) * r.y * g);
            tile[nq + q * 4 + 2][cl] = f2bs((v.z - m.z) * r.z * g);
            tile[nq + q * 4 + 3][cl] = f2bs((v.w - m.w) * r.w * g);
        }
        __syncthreads();
        unsigned short* dst = xnT + ((size_t)b * NPOS + n0 + n) * NDIM + c0 + cq;
        *(uint4*)dst       = *(const uint4*)&tile[n][cq];
        *(uint4*)(dst + 8) = *(const uint4*)&tile[n][cq + 8];
        __syncthreads();
    }
}

// ---------------- K1b: f32 -> bf16 cast, both weights in one grid ---------
__global__ __launch_bounds__(256) void castw2_kernel(
    const float* __restrict__ wq, unsigned short* __restrict__ wqb,
    const float* __restrict__ wo, unsigned short* __restrict__ wob)
{
    const int n1 = INNER * NDIM / 4;
    int i = blockIdx.x * 256 + threadIdx.x;
    const float* src; unsigned short* dst; int j;
    if (i < n1) { src = wq; dst = wqb; j = i; }
    else        { src = wo; dst = wob; j = i - n1; }
    float4 v = ((const float4*)src)[j];
    ushort4 u;
    u.x = f2bs(v.x); u.y = f2bs(v.y); u.z = f2bs(v.z); u.w = f2bs(v.w);
    ((ushort4*)dst)[j] = u;
}

// ---------------- K2: QKV GEMM (MFMA bf16, async LDS staging) -------------
// LDS tiles: [128 rows][4 slots x 8 shorts], slot = chunk ^ ((row>>1)&3)
__global__ __launch_bounds__(256) void qkv_mfma_kernel(
    const unsigned short* __restrict__ wq, const unsigned short* __restrict__ xnT,
    unsigned short* __restrict__ qT, unsigned short* __restrict__ kT,
    unsigned short* __restrict__ vv)
{
    __shared__ __align__(16) unsigned short smem[4 * 64 * 72];  // 36864 B
    unsigned short* At = smem;          // 128x32 shorts (8 KB), swizzled
    unsigned short* Bt = smem + 4096;   // 128x32 shorts (8 KB), swizzled

    const int b = blockIdx.z;
    const int m0 = blockIdx.y * 128, n0 = blockIdx.x * 128;
    const int t = threadIdx.x, w = t >> 6, lane = t & 63;
    const int l15 = lane & 15, quad = lane >> 4;
    const int wm = (w >> 1) * 64, wn = (w & 1) * 64;
    const unsigned short* Abase = wq + (size_t)m0 * NDIM;
    const unsigned short* Bbase = xnT + ((size_t)b * NPOS + n0) * NDIM;

    const int rl = lane >> 2, sl = lane & 3;
    const int cw = (sl ^ ((rl >> 1) & 3)) * 8;      // write-side global chunk offset
    const int sA = (quad ^ ((l15 >> 1) & 3)) * 8;   // read-side LDS slot offset

    f4v acc[4][4];
#pragma unroll
    for (int i = 0; i < 4; ++i)
#pragma unroll
        for (int j = 0; j < 4; ++j) { acc[i][j][0]=0.f; acc[i][j][1]=0.f; acc[i][j][2]=0.f; acc[i][j][3]=0.f; }

    for (int k0 = 0; k0 < NDIM; k0 += 32) {
        __syncthreads();                            // prev reads done
#pragma unroll
        for (int e = 0; e < 2; ++e) {
            const int seg = w * 2 + e;              // 0..7, 16 rows each
            const int r = seg * 16 + rl;
            gl_lds16(Abase + (size_t)r * NDIM + k0 + cw, At + seg * 512);
            gl_lds16(Bbase + (size_t)r * NDIM + k0 + cw, Bt + seg * 512);
        }
        __syncthreads();                            // vmcnt drain + barrier
        bf8v af[4], bfr[4];
#pragma unroll
        for (int ms = 0; ms < 4; ++ms) af[ms]  = *(const bf8v*)&At[(wm + ms * 16 + l15) * 32 + sA];
#pragma unroll
        for (int ns = 0; ns < 4; ++ns) bfr[ns] = *(const bf8v*)&Bt[(wn + ns * 16 + l15) * 32 + sA];
#pragma unroll
        for (int ms = 0; ms < 4; ++ms)
#pragma unroll
            for (int ns = 0; ns < 4; ++ns)
                acc[ms][ns] = mfma16(af[ms], bfr[ns], acc[ms][ns]);
    }
    __syncthreads();   // done with At/Bt; smem reusable as bounce

    const int sec = m0 >> 9;         // 0=q, 1=k, 2=v
    const int om  = m0 & 511;
    if (sec == 2) {
        unsigned short* vbase = vv + ((size_t)b * NDIM + om) * NPOS + n0;
#pragma unroll
        for (int ms = 0; ms < 4; ++ms)
#pragma unroll
            for (int r = 0; r < 4; ++r) {
                int m = wm + ms * 16 + quad * 4 + r;
#pragma unroll
                for (int ns = 0; ns < 4; ++ns)
                    vbase[(size_t)m * NPOS + wn + ns * 16 + l15] = f2bs(acc[ms][ns][r]);
            }
    } else {
        const float qsc = (sec == 0) ? 0.125f : 1.0f;   // fold dim_head^-0.5 into Q
        unsigned short* gT = (sec == 0 ? qT : kT) + ((size_t)b * NPOS + n0) * NDIM + om;
        unsigned short (*bw)[72] = (unsigned short(*)[72])(smem + w * 64 * 72);
#pragma unroll
        for (int ms = 0; ms < 4; ++ms)
#pragma unroll
            for (int ns = 0; ns < 4; ++ns)
#pragma unroll
                for (int r = 0; r < 4; ++r)
                    bw[ns * 16 + l15][ms * 16 + quad * 4 + r] = f2bs(acc[ms][ns][r] * qsc);
        unsigned short* dst = gT + (size_t)(wn + lane) * NDIM + wm;
#pragma unroll
        for (int q2 = 0; q2 < 8; ++q2)
            *(uint4*)(dst + q2 * 8) = *(const uint4*)&bw[lane][q2 * 8];
    }
}

// ---------------- K3: flash attention v4 (barrier-free, frags from L1/L2) -
// S^T = K·Q^T (A=K from global, B=Q regs); P in wave-private LDS stripe;
// l via constant ones B-fragment. ZERO __syncthreads.
__global__ __launch_bounds__(256) void attn_mfma4_kernel(
    const unsigned short* __restrict__ qT, const unsigned short* __restrict__ kT,
    const unsigned short* __restrict__ vv, unsigned short* __restrict__ attnT)
{
    __shared__ __align__(16) unsigned short Ps[4][32][72];   // wave-private stripes

    // XCD swizzle: blk&7 = bh low bits; a CU's blocks share one (b,h) so the
    // 16KB K/V tile is L1-resident across its waves.
    const int blk = blockIdx.x;                 // 512 blocks
    const int xg = blk & 7, rr = blk >> 3;
    const int i0 = (rr & 7) * 128;
    const int bh = ((rr >> 3) << 3) | xg;
    const int b = bh >> 3, h = bh & 7;

    const int t = threadIdx.x, w = t >> 6, lane = t & 63;
    const int l15 = lane & 15, quad = lane >> 4;

    const unsigned short* kbase = kT + (size_t)b * NPOS * NDIM + h * DHEAD;
    const unsigned short* vbase = vv + ((size_t)b * NDIM + h * DHEAD) * NPOS;

    // Q fragments (B-operand): wave covers 32 rows, two 16-row groups
    bf8v bq[2][2];
#pragma unroll
    for (int g = 0; g < 2; ++g) {
        const unsigned short* qrow =
            qT + ((size_t)b * NPOS + i0 + w * 32 + g * 16 + l15) * NDIM + h * DHEAD;
        bq[g][0] = *(const bf8v*)(qrow + quad * 8);
        bq[g][1] = *(const bf8v*)(qrow + 32 + quad * 8);
    }

    bf8v bones;   // constant ones fragment: l = sum_j P[i][j]
#pragma unroll
    for (int e = 0; e < 8; ++e) bones[e] = (short)0x3F80;

    f4v oc[2][5];
#pragma unroll
    for (int mg = 0; mg < 2; ++mg)
#pragma unroll
        for (int cs = 0; cs < 5; ++cs) { oc[mg][cs][0]=0.f; oc[mg][cs][1]=0.f; oc[mg][cs][2]=0.f; oc[mg][cs][3]=0.f; }

    for (int j0 = 0; j0 < NPOS; j0 += 64) {
        // S^T[j][i]: A = K rows straight from global (L1-cached across waves)
#pragma unroll
        for (int jt = 0; jt < 4; ++jt) {
            const unsigned short* krow = kbase + (size_t)(j0 + jt * 16 + l15) * NDIM;
            bf8v ak0 = *(const bf8v*)(krow + quad * 8);
            bf8v ak1 = *(const bf8v*)(krow + 32 + quad * 8);
#pragma unroll
            for (int g = 0; g < 2; ++g) {
                f4v s; s[0]=0.f; s[1]=0.f; s[2]=0.f; s[3]=0.f;
                s = mfma16(ak0, bq[g][0], s);
                s = mfma16(ak1, bq[g][1], s);
                ushort4 pu;
                pu.x = f2bs(__expf(fminf(s[0], 60.f)));
                pu.y = f2bs(__expf(fminf(s[1], 60.f)));
                pu.z = f2bs(__expf(fminf(s[2], 60.f)));
                pu.w = f2bs(__expf(fminf(s[3], 60.f)));
                // D rows j = jt*16+quad*4+r, col i_local = g*16+l15
                *(ushort4*)&Ps[w][g * 16 + l15][jt * 16 + quad * 4] = pu;
            }
        }
        // P as A-operand (same-wave LDS round trip; lgkmcnt handled by compiler)
        bf8v ap[2][2];
#pragma unroll
        for (int mg = 0; mg < 2; ++mg) {
            ap[mg][0] = *(const bf8v*)&Ps[w][mg * 16 + l15][quad * 8];
            ap[mg][1] = *(const bf8v*)&Ps[w][mg * 16 + l15][32 + quad * 8];
        }
        // O[i][c] += P·V^T; V fragments straight from global (L1-cached)
#pragma unroll
        for (int cs = 0; cs < 4; ++cs) {
            const unsigned short* vrow = vbase + (size_t)(cs * 16 + l15) * NPOS + j0;
            bf8v bv0 = *(const bf8v*)(vrow + quad * 8);
            bf8v bv1 = *(const bf8v*)(vrow + 32 + quad * 8);
#pragma unroll
            for (int mg = 0; mg < 2; ++mg) {
                oc[mg][cs] = mfma16(ap[mg][0], bv0, oc[mg][cs]);
                oc[mg][cs] = mfma16(ap[mg][1], bv1, oc[mg][cs]);
            }
        }
#pragma unroll
        for (int mg = 0; mg < 2; ++mg) {
            oc[mg][4] = mfma16(ap[mg][0], bones, oc[mg][4]);
            oc[mg][4] = mfma16(ap[mg][1], bones, oc[mg][4]);
        }
    }

#pragma unroll
    for (int mg = 0; mg < 2; ++mg) {
        float inv[4];
#pragma unroll
        for (int r = 0; r < 4; ++r) inv[r] = 1.0f / oc[mg][4][r];   // l lane-local
        unsigned short* dst =
            attnT + ((size_t)b * NPOS + i0 + w * 32 + mg * 16) * NDIM + h * DHEAD;
#pragma unroll
        for (int cs = 0; cs < 4; ++cs)
#pragma unroll
            for (int r = 0; r < 4; ++r)
                dst[(size_t)(quad * 4 + r) * NDIM + cs * 16 + l15] = f2bs(oc[mg][cs][r] * inv[r]);
    }
}

// ---------------- K4: out projection (MFMA, async staging) + residual -----
__global__ __launch_bounds__(256) void out_mfma_kernel(
    const unsigned short* __restrict__ wo, const unsigned short* __restrict__ attnT,
    const float* __restrict__ x, float* __restrict__ outp)
{
    __shared__ __align__(16) unsigned short smem[8192];   // A 128x32 | B 128x32
    unsigned short* At = smem;
    unsigned short* Bt = smem + 4096;

    const int b = blockIdx.z;
    const int m0 = blockIdx.y * 128, n0 = blockIdx.x * 128;
    const int t = threadIdx.x, w = t >> 6, lane = t & 63;
    const int l15 = lane & 15, quad = lane >> 4;
    const int wm = (w >> 1) * 64, wn = (w & 1) * 64;
    const unsigned short* Abase = wo + (size_t)m0 * NDIM;
    const unsigned short* Bbase = attnT + ((size_t)b * NPOS + n0) * NDIM;

    const int rl = lane >> 2, sl = lane & 3;
    const int cw = (sl ^ ((rl >> 1) & 3)) * 8;
    const int sA = (quad ^ ((l15 >> 1) & 3)) * 8;

    f4v acc[4][4];
#pragma unroll
    for (int i = 0; i < 4; ++i)
#pragma unroll
        for (int j = 0; j < 4; ++j) { acc[i][j][0]=0.f; acc[i][j][1]=0.f; acc[i][j][2]=0.f; acc[i][j][3]=0.f; }

    for (int k0 = 0; k0 < NDIM; k0 += 32) {
        __syncthreads();
#pragma unroll
        for (int e = 0; e < 2; ++e) {
            const int seg = w * 2 + e;
            const int r = seg * 16 + rl;
            gl_lds16(Abase + (size_t)r * NDIM + k0 + cw, At + seg * 512);
            gl_lds16(Bbase + (size_t)r * NDIM + k0 + cw, Bt + seg * 512);
        }
        __syncthreads();
        bf8v af[4], bfr[4];
#pragma unroll
        for (int ms = 0; ms < 4; ++ms) af[ms]  = *(const bf8v*)&At[(wm + ms * 16 + l15) * 32 + sA];
#pragma unroll
        for (int ns = 0; ns < 4; ++ns) bfr[ns] = *(const bf8v*)&Bt[(wn + ns * 16 + l15) * 32 + sA];
#pragma unroll
        for (int ms = 0; ms < 4; ++ms)
#pragma unroll
            for (int ns = 0; ns < 4; ++ns)
                acc[ms][ns] = mfma16(af[ms], bfr[ns], acc[ms][ns]);
    }
    const float* xb = x + ((size_t)b * NDIM + m0) * NPOS + n0;
    float* ob = outp + ((size_t)b * NDIM + m0) * NPOS + n0;
#pragma unroll
    for (int ms = 0; ms < 4; ++ms)
#pragma unroll
        for (int r = 0; r < 4; ++r) {
            int m = wm + ms * 16 + quad * 4 + r;
#pragma unroll
            for (int ns = 0; ns < 4; ++ns) {
                int n = wn + ns * 16 + l15;
                ob[(size_t)m * NPOS + n] = acc[ms][ns][r] + xb[(size_t)m * NPOS + n];
            }
        }
}

extern "C" void kernel_launch(void* const* d_in, const int* in_sizes, int n_in,
                              void* d_out, int out_size, void* d_ws, size_t ws_size,
                              hipStream_t stream) {
    const float* x     = (const float*)d_in[0];   // [8][512][32][32] f32
    const float* gamma = (const float*)d_in[1];   // [512] f32
    const float* w_qkv = (const float*)d_in[2];   // [1536][512] f32
    const float* w_out = (const float*)d_in[3];   // [512][512] f32
    float* out = (float*)d_out;                   // [8][512][32][32] f32

    unsigned short* xnT = (unsigned short*)d_ws;             // 8*1024*512 bf16
    unsigned short* wqb = xnT + (size_t)NB * NPOS * NDIM;    // 1536*512
    unsigned short* wob = wqb + (size_t)INNER * NDIM;        // 512*512
    unsigned short* qTw = wob + (size_t)NDIM * NDIM;         // 8*1024*512
    unsigned short* kTw = qTw + (size_t)NB * NPOS * NDIM;
    unsigned short* vvw = kTw + (size_t)NB * NPOS * NDIM;
    unsigned short* aTw = vvw + (size_t)NB * NPOS * NDIM;

    ln_xnorm_kernel<<<dim3(NPOS / 64, NB), 256, 0, stream>>>(x, gamma, xnT);
    castw2_kernel<<<(INNER * NDIM + NDIM * NDIM) / 4 / 256, 256, 0, stream>>>(
        w_qkv, wqb, w_out, wob);
    qkv_mfma_kernel<<<dim3(NPOS / 128, INNER / 128, NB), 256, 0, stream>>>(
        wqb, xnT, qTw, kTw, vvw);
    attn_mfma4_kernel<<<512, 256, 0, stream>>>(qTw, kTw, vvw, aTw);
    out_mfma_kernel<<<dim3(NPOS / 128, NDIM / 128, NB), 256, 0, stream>>>(wob, aTw, x, out);
}

// Round 8
// 166.960 us; speedup vs baseline: 1.1088x; 1.1088x over previous
//
#include <hip/hip_runtime.h>
#include <hip/hip_bf16.h>

#define NDIM   512
#define NPOS   1024   // 32*32
#define NB     8
#define INNER  1536
#define DHEAD  64

typedef __attribute__((ext_vector_type(8))) short bf8v;   // 8 bf16 = 4 VGPRs
typedef __attribute__((ext_vector_type(4))) float f4v;

__device__ __forceinline__ f4v mfma16(bf8v a, bf8v b, f4v c) {
    return __builtin_amdgcn_mfma_f32_16x16x32_bf16(a, b, c, 0, 0, 0);
}

__device__ __forceinline__ unsigned short f2bs(float v) {
    __hip_bfloat16 h = __float2bfloat16(v);   // RNE
    return *reinterpret_cast<unsigned short*>(&h);
}

// async global->LDS, 16B per lane; lds dst = wave-uniform base + lane*16
__device__ __forceinline__ void gl_lds16(const unsigned short* g, unsigned short* l) {
    __builtin_amdgcn_global_load_lds(
        (const __attribute__((address_space(1))) void*)g,
        (__attribute__((address_space(3))) void*)l,
        16, 0, 0);
}

// ---------------- K1: fused LN stats + normalize + cast + transpose -------
__global__ __launch_bounds__(256) void ln_xnorm_kernel(
    const float* __restrict__ x, const float* __restrict__ gamma,
    unsigned short* __restrict__ xnT)
{
    __shared__ float ssum[4][64];
    __shared__ float ssq[4][64];
    __shared__ float mean_s[64];
    __shared__ float rstd_s[64];
    __shared__ unsigned short tile[64][72];

    const int b = blockIdx.y;
    const int n0 = blockIdx.x * 64;
    const int t = threadIdx.x;

    {
        const int ln = t & 63, cg = t >> 6;
        const float* xp = x + (size_t)b * NDIM * NPOS + n0 + ln;
        float s = 0.f, ss = 0.f;
        for (int c = cg * 128; c < cg * 128 + 128; ++c) {
            float v = xp[(size_t)c * NPOS];
            s += v; ss += v * v;
        }
        ssum[cg][ln] = s; ssq[cg][ln] = ss;
    }
    __syncthreads();
    if (t < 64) {
        float st = ssum[0][t] + ssum[1][t] + ssum[2][t] + ssum[3][t];
        float sq = ssq[0][t] + ssq[1][t] + ssq[2][t] + ssq[3][t];
        float m = st * (1.0f / NDIM);
        float var = sq * (1.0f / NDIM) - m * m;
        mean_s[t] = m;
        rstd_s[t] = rsqrtf(var + 1e-5f);
    }
    __syncthreads();

    const int cl = t >> 2, nq = (t & 3) * 16;
    const int n = t >> 2, cq = (t & 3) * 16;
    for (int c0 = 0; c0 < NDIM; c0 += 64) {
        const float g = gamma[c0 + cl];
        const float* xp = x + ((size_t)b * NDIM + c0 + cl) * NPOS + n0 + nq;
#pragma unroll
        for (int q = 0; q < 4; ++q) {
            float4 v = *(const float4*)(xp + q * 4);
            float4 m = *(const float4*)&mean_s[nq + q * 4];
            float4 r = *(const float4*)&rstd_s[nq + q * 4];
            tile[nq + q * 4 + 0][cl] = f2bs((v.x - m.x) * r.x * g);
            tile[nq + q * 4 + 1][cl] = f2bs((v.y - m.y) * r.y * g);
            tile[nq + q * 4 + 2][cl] = f2bs((v.z - m.z) * r.z * g);
            tile[nq + q * 4 + 3][cl] = f2bs((v.w - m.w) * r.w * g);
        }
        __syncthreads();
        unsigned short* dst = xnT + ((size_t)b * NPOS + n0 + n) * NDIM + c0 + cq;
        *(uint4*)dst       = *(const uint4*)&tile[n][cq];
        *(uint4*)(dst + 8) = *(const uint4*)&tile[n][cq + 8];
        __syncthreads();
    }
}

// ---------------- K1b: f32 -> bf16 cast, both weights in one grid ---------
__global__ __launch_bounds__(256) void castw2_kernel(
    const float* __restrict__ wq, unsigned short* __restrict__ wqb,
    const float* __restrict__ wo, unsigned short* __restrict__ wob)
{
    const int n1 = INNER * NDIM / 4;
    int i = blockIdx.x * 256 + threadIdx.x;
    const float* src; unsigned short* dst; int j;
    if (i < n1) { src = wq; dst = wqb; j = i; }
    else        { src = wo; dst = wob; j = i - n1; }
    float4 v = ((const float4*)src)[j];
    ushort4 u;
    u.x = f2bs(v.x); u.y = f2bs(v.y); u.z = f2bs(v.z); u.w = f2bs(v.w);
    ((ushort4*)dst)[j] = u;
}

// ---------------- K2: QKV GEMM (MFMA bf16, async LDS staging) -------------
__global__ __launch_bounds__(256) void qkv_mfma_kernel(
    const unsigned short* __restrict__ wq, const unsigned short* __restrict__ xnT,
    unsigned short* __restrict__ qT, unsigned short* __restrict__ kT,
    unsigned short* __restrict__ vv)
{
    __shared__ __align__(16) unsigned short smem[4 * 64 * 72];  // 36864 B
    unsigned short* At = smem;          // 128x32 shorts (8 KB), swizzled
    unsigned short* Bt = smem + 4096;   // 128x32 shorts (8 KB), swizzled

    const int b = blockIdx.z;
    const int m0 = blockIdx.y * 128, n0 = blockIdx.x * 128;
    const int t = threadIdx.x, w = t >> 6, lane = t & 63;
    const int l15 = lane & 15, quad = lane >> 4;
    const int wm = (w >> 1) * 64, wn = (w & 1) * 64;
    const unsigned short* Abase = wq + (size_t)m0 * NDIM;
    const unsigned short* Bbase = xnT + ((size_t)b * NPOS + n0) * NDIM;

    const int rl = lane >> 2, sl = lane & 3;
    const int cw = (sl ^ ((rl >> 1) & 3)) * 8;      // write-side global chunk offset
    const int sA = (quad ^ ((l15 >> 1) & 3)) * 8;   // read-side LDS slot offset

    f4v acc[4][4];
#pragma unroll
    for (int i = 0; i < 4; ++i)
#pragma unroll
        for (int j = 0; j < 4; ++j) { acc[i][j][0]=0.f; acc[i][j][1]=0.f; acc[i][j][2]=0.f; acc[i][j][3]=0.f; }

    for (int k0 = 0; k0 < NDIM; k0 += 32) {
        __syncthreads();                            // prev reads done
#pragma unroll
        for (int e = 0; e < 2; ++e) {
            const int seg = w * 2 + e;              // 0..7, 16 rows each
            const int r = seg * 16 + rl;
            gl_lds16(Abase + (size_t)r * NDIM + k0 + cw, At + seg * 512);
            gl_lds16(Bbase + (size_t)r * NDIM + k0 + cw, Bt + seg * 512);
        }
        __syncthreads();                            // vmcnt drain + barrier
        bf8v af[4], bfr[4];
#pragma unroll
        for (int ms = 0; ms < 4; ++ms) af[ms]  = *(const bf8v*)&At[(wm + ms * 16 + l15) * 32 + sA];
#pragma unroll
        for (int ns = 0; ns < 4; ++ns) bfr[ns] = *(const bf8v*)&Bt[(wn + ns * 16 + l15) * 32 + sA];
#pragma unroll
        for (int ms = 0; ms < 4; ++ms)
#pragma unroll
            for (int ns = 0; ns < 4; ++ns)
                acc[ms][ns] = mfma16(af[ms], bfr[ns], acc[ms][ns]);
    }
    __syncthreads();   // done with At/Bt; smem reusable as bounce

    const int sec = m0 >> 9;         // 0=q, 1=k, 2=v
    const int om  = m0 & 511;
    if (sec == 2) {
        unsigned short* vbase = vv + ((size_t)b * NDIM + om) * NPOS + n0;
#pragma unroll
        for (int ms = 0; ms < 4; ++ms)
#pragma unroll
            for (int r = 0; r < 4; ++r) {
                int m = wm + ms * 16 + quad * 4 + r;
#pragma unroll
                for (int ns = 0; ns < 4; ++ns)
                    vbase[(size_t)m * NPOS + wn + ns * 16 + l15] = f2bs(acc[ms][ns][r]);
            }
    } else {
        const float qsc = (sec == 0) ? 0.125f : 1.0f;   // fold dim_head^-0.5 into Q
        unsigned short* gT = (sec == 0 ? qT : kT) + ((size_t)b * NPOS + n0) * NDIM + om;
        unsigned short (*bw)[72] = (unsigned short(*)[72])(smem + w * 64 * 72);
#pragma unroll
        for (int ms = 0; ms < 4; ++ms)
#pragma unroll
            for (int ns = 0; ns < 4; ++ns)
#pragma unroll
                for (int r = 0; r < 4; ++r)
                    bw[ns * 16 + l15][ms * 16 + quad * 4 + r] = f2bs(acc[ms][ns][r] * qsc);
        unsigned short* dst = gT + (size_t)(wn + lane) * NDIM + wm;
#pragma unroll
        for (int q2 = 0; q2 < 8; ++q2)
            *(uint4*)(dst + q2 * 8) = *(const uint4*)&bw[lane][q2 * 8];
    }
}

// ---------------- K3: flash attention v5 ----------------------------------
// K staged in LDS (register-prefetch pipeline, 2 barriers/iter).
// V fragments direct from global (issued early, latency hidden under QK+exp,
// served by XCD L2 thanks to swizzle). l via constant ones B-fragment.
__global__ __launch_bounds__(256) void attn_mfma5_kernel(
    const unsigned short* __restrict__ qT, const unsigned short* __restrict__ kT,
    const unsigned short* __restrict__ vv, unsigned short* __restrict__ attnT)
{
    __shared__ unsigned short Ks[64][72];            // [j][c]
    __shared__ __align__(16) unsigned short Ps[4][32][72];   // wave-private

    // XCD swizzle: blk&7 = h so all 8 (b)x8(i-tile) blocks of a given h share
    // an XCD; per-XCD K/V working set 2MB < 4MB L2.
    const int blk = blockIdx.x;                 // 512 blocks
    const int xg = blk & 7, rr = blk >> 3;
    const int i0 = (rr & 7) * 128;
    const int bh = ((rr >> 3) << 3) | xg;
    const int b = bh >> 3, h = bh & 7;

    const int t = threadIdx.x, w = t >> 6, lane = t & 63;
    const int l15 = lane & 15, quad = lane >> 4;

    const unsigned short* kbase = kT + (size_t)b * NPOS * NDIM + h * DHEAD;
    const unsigned short* vbase = vv + ((size_t)b * NDIM + h * DHEAD) * NPOS;

    // Q fragments (B-operand): wave covers 32 rows, two 16-row groups
    bf8v bq[2][2];
#pragma unroll
    for (int g = 0; g < 2; ++g) {
        const unsigned short* qrow =
            qT + ((size_t)b * NPOS + i0 + w * 32 + g * 16 + l15) * NDIM + h * DHEAD;
        bq[g][0] = *(const bf8v*)(qrow + quad * 8);
        bq[g][1] = *(const bf8v*)(qrow + 32 + quad * 8);
    }

    bf8v bones;   // constant ones fragment: l = sum_j P[i][j]
#pragma unroll
    for (int e = 0; e < 8; ++e) bones[e] = (short)0x3F80;

    // K staging indices: row t>>2, col chunk (t&3)*16
    const int jr = t >> 2, cq = (t & 3) * 16;

    // prefetch K tile 0
    uint4 ka, kb2;
    {
        const unsigned short* kp = kbase + (size_t)jr * NDIM + cq;
        ka = *(const uint4*)kp;  kb2 = *(const uint4*)(kp + 8);
    }

    f4v oc[2][5];
#pragma unroll
    for (int mg = 0; mg < 2; ++mg)
#pragma unroll
        for (int cs = 0; cs < 5; ++cs) { oc[mg][cs][0]=0.f; oc[mg][cs][1]=0.f; oc[mg][cs][2]=0.f; oc[mg][cs][3]=0.f; }

    for (int j0 = 0; j0 < NPOS; j0 += 64) {
        __syncthreads();                       // prev iter done reading Ks
        *(uint4*)&Ks[jr][cq] = ka;  *(uint4*)&Ks[jr][cq + 8] = kb2;
        __syncthreads();
        if (j0 + 64 < NPOS) {                  // prefetch next K tile under compute
            const unsigned short* kp = kbase + (size_t)(j0 + 64 + jr) * NDIM + cq;
            ka = *(const uint4*)kp;  kb2 = *(const uint4*)(kp + 8);
        }
        // V fragments for THIS tile, direct from global: issued now, used after
        // QK+exp (~300 cyc of independent work) -> L2 latency hidden.
        bf8v bv[4][2];
#pragma unroll
        for (int cs = 0; cs < 4; ++cs) {
            const unsigned short* vrow = vbase + (size_t)(cs * 16 + l15) * NPOS + j0;
            bv[cs][0] = *(const bf8v*)(vrow + quad * 8);
            bv[cs][1] = *(const bf8v*)(vrow + 32 + quad * 8);
        }

        // S^T[j][i]: A = K from LDS, B = Q regs; scale pre-folded into Q
#pragma unroll
        for (int jt = 0; jt < 4; ++jt) {
            bf8v ak0 = *(const bf8v*)&Ks[jt * 16 + l15][quad * 8];
            bf8v ak1 = *(const bf8v*)&Ks[jt * 16 + l15][32 + quad * 8];
#pragma unroll
            for (int g = 0; g < 2; ++g) {
                f4v s; s[0]=0.f; s[1]=0.f; s[2]=0.f; s[3]=0.f;
                s = mfma16(ak0, bq[g][0], s);
                s = mfma16(ak1, bq[g][1], s);
                ushort4 pu;
                pu.x = f2bs(__expf(fminf(s[0], 60.f)));
                pu.y = f2bs(__expf(fminf(s[1], 60.f)));
                pu.z = f2bs(__expf(fminf(s[2], 60.f)));
                pu.w = f2bs(__expf(fminf(s[3], 60.f)));
                *(ushort4*)&Ps[w][g * 16 + l15][jt * 16 + quad * 4] = pu;
            }
        }
        // P as A-operand (same-wave LDS round trip)
        bf8v ap[2][2];
#pragma unroll
        for (int mg = 0; mg < 2; ++mg) {
            ap[mg][0] = *(const bf8v*)&Ps[w][mg * 16 + l15][quad * 8];
            ap[mg][1] = *(const bf8v*)&Ps[w][mg * 16 + l15][32 + quad * 8];
        }
#pragma unroll
        for (int cs = 0; cs < 4; ++cs)
#pragma unroll
            for (int mg = 0; mg < 2; ++mg) {
                oc[mg][cs] = mfma16(ap[mg][0], bv[cs][0], oc[mg][cs]);
                oc[mg][cs] = mfma16(ap[mg][1], bv[cs][1], oc[mg][cs]);
            }
#pragma unroll
        for (int mg = 0; mg < 2; ++mg) {
            oc[mg][4] = mfma16(ap[mg][0], bones, oc[mg][4]);
            oc[mg][4] = mfma16(ap[mg][1], bones, oc[mg][4]);
        }
    }

#pragma unroll
    for (int mg = 0; mg < 2; ++mg) {
        float inv[4];
#pragma unroll
        for (int r = 0; r < 4; ++r) inv[r] = 1.0f / oc[mg][4][r];   // l lane-local
        unsigned short* dst =
            attnT + ((size_t)b * NPOS + i0 + w * 32 + mg * 16) * NDIM + h * DHEAD;
#pragma unroll
        for (int cs = 0; cs < 4; ++cs)
#pragma unroll
            for (int r = 0; r < 4; ++r)
                dst[(size_t)(quad * 4 + r) * NDIM + cs * 16 + l15] = f2bs(oc[mg][cs][r] * inv[r]);
    }
}

// ---------------- K4: out projection (MFMA, async staging) + residual -----
__global__ __launch_bounds__(256) void out_mfma_kernel(
    const unsigned short* __restrict__ wo, const unsigned short* __restrict__ attnT,
    const float* __restrict__ x, float* __restrict__ outp)
{
    __shared__ __align__(16) unsigned short smem[8192];   // A 128x32 | B 128x32
    unsigned short* At = smem;
    unsigned short* Bt = smem + 4096;

    const int b = blockIdx.z;
    const int m0 = blockIdx.y * 128, n0 = blockIdx.x * 128;
    const int t = threadIdx.x, w = t >> 6, lane = t & 63;
    const int l15 = lane & 15, quad = lane >> 4;
    const int wm = (w >> 1) * 64, wn = (w & 1) * 64;
    const unsigned short* Abase = wo + (size_t)m0 * NDIM;
    const unsigned short* Bbase = attnT + ((size_t)b * NPOS + n0) * NDIM;

    const int rl = lane >> 2, sl = lane & 3;
    const int cw = (sl ^ ((rl >> 1) & 3)) * 8;
    const int sA = (quad ^ ((l15 >> 1) & 3)) * 8;

    f4v acc[4][4];
#pragma unroll
    for (int i = 0; i < 4; ++i)
#pragma unroll
        for (int j = 0; j < 4; ++j) { acc[i][j][0]=0.f; acc[i][j][1]=0.f; acc[i][j][2]=0.f; acc[i][j][3]=0.f; }

    for (int k0 = 0; k0 < NDIM; k0 += 32) {
        __syncthreads();
#pragma unroll
        for (int e = 0; e < 2; ++e) {
            const int seg = w * 2 + e;
            const int r = seg * 16 + rl;
            gl_lds16(Abase + (size_t)r * NDIM + k0 + cw, At + seg * 512);
            gl_lds16(Bbase + (size_t)r * NDIM + k0 + cw, Bt + seg * 512);
        }
        __syncthreads();
        bf8v af[4], bfr[4];
#pragma unroll
        for (int ms = 0; ms < 4; ++ms) af[ms]  = *(const bf8v*)&At[(wm + ms * 16 + l15) * 32 + sA];
#pragma unroll
        for (int ns = 0; ns < 4; ++ns) bfr[ns] = *(const bf8v*)&Bt[(wn + ns * 16 + l15) * 32 + sA];
#pragma unroll
        for (int ms = 0; ms < 4; ++ms)
#pragma unroll
            for (int ns = 0; ns < 4; ++ns)
                acc[ms][ns] = mfma16(af[ms], bfr[ns], acc[ms][ns]);
    }
    const float* xb = x + ((size_t)b * NDIM + m0) * NPOS + n0;
    float* ob = outp + ((size_t)b * NDIM + m0) * NPOS + n0;
#pragma unroll
    for (int ms = 0; ms < 4; ++ms)
#pragma unroll
        for (int r = 0; r < 4; ++r) {
            int m = wm + ms * 16 + quad * 4 + r;
#pragma unroll
            for (int ns = 0; ns < 4; ++ns) {
                int n = wn + ns * 16 + l15;
                ob[(size_t)m * NPOS + n] = acc[ms][ns][r] + xb[(size_t)m * NPOS + n];
            }
        }
}

extern "C" void kernel_launch(void* const* d_in, const int* in_sizes, int n_in,
                              void* d_out, int out_size, void* d_ws, size_t ws_size,
                              hipStream_t stream) {
    const float* x     = (const float*)d_in[0];   // [8][512][32][32] f32
    const float* gamma = (const float*)d_in[1];   // [512] f32
    const float* w_qkv = (const float*)d_in[2];   // [1536][512] f32
    const float* w_out = (const float*)d_in[3];   // [512][512] f32
    float* out = (float*)d_out;                   // [8][512][32][32] f32

    unsigned short* xnT = (unsigned short*)d_ws;             // 8*1024*512 bf16
    unsigned short* wqb = xnT + (size_t)NB * NPOS * NDIM;    // 1536*512
    unsigned short* wob = wqb + (size_t)INNER * NDIM;        // 512*512
    unsigned short* qTw = wob + (size_t)NDIM * NDIM;         // 8*1024*512
    unsigned short* kTw = qTw + (size_t)NB * NPOS * NDIM;
    unsigned short* vvw = kTw + (size_t)NB * NPOS * NDIM;
    unsigned short* aTw = vvw + (size_t)NB * NPOS * NDIM;

    ln_xnorm_kernel<<<dim3(NPOS / 64, NB), 256, 0, stream>>>(x, gamma, xnT);
    castw2_kernel<<<(INNER * NDIM + NDIM * NDIM) / 4 / 256, 256, 0, stream>>>(
        w_qkv, wqb, w_out, wob);
    qkv_mfma_kernel<<<dim3(NPOS / 128, INNER / 128, NB), 256, 0, stream>>>(
        wqb, xnT, qTw, kTw, vvw);
    attn_mfma5_kernel<<<512, 256, 0, stream>>>(qTw, kTw, vvw, aTw);
    out_mfma_kernel<<<dim3(NPOS / 128, NDIM / 128, NB), 256, 0, stream>>>(wob, aTw, x, out);
}